// Round 5
// baseline (125.855 us; speedup 1.0000x reference)
//
#include <hip/hip_runtime.h>
#include <hip/hip_fp16.h>

// L=8 layers, H=512, K=16 links, N_IN=512, B=8192; out = last 512 cols (fp32).
#define LAYERS 8
#define H      512
#define K      16
#define N_IN   512
#define BATCH  8192
#define R      8      // batch rows per block; 8 x f16 = 16 B -> one ds_read_b128 per gather
#define NT     512    // 8 waves/block; 64 KB LDS -> 2 blocks/CU -> 16 waves/CU
// Layer l gathers from cols [0, 512+512*l); max l=7 -> cols < 4096. Layer 7's
// output is never gathered -> straight to global. LDS = 4096*16 B = 64 KB.
#define LDS_COLS 4096

// History:
//  R3/R4: NT=1024 spills regardless of __launch_bounds__. Stay at NT=512.
//  R5/R7: bank-group sort+stagger prep: conflicts only -12% (static lane perms
//    can't debias the 64-lane multinomial) and the extra dispatch cost ~10us
//    e2e. Reverted.
//  R8: g[2][4] rolling double-buffer: compiler collapsed it (VGPR 60), did NOT
//    deepen the read queue, dispatches 50->55-61us. Lesson: scheduler sinks
//    reads toward uses to save pressure unless pinned.
//  R9 (this): LDS pipe ~68% busy (34us of work in a 50us dispatch) -> feed it.
//    Burst-issue 8 ds_read_b128, sched_barrier(0) to pin issue order, then
//    consume; x2 per layer. Register-counted ~119 VGPR <= 128 cap from
//    __launch_bounds__(512,4) (16 waves/CU, matches the 2-block LDS limit).

__global__ __launch_bounds__(NT, 4)
void ffn_fused_kernel(const float* __restrict__ x,
                      const int*   __restrict__ link_idx,
                      const float* __restrict__ weights,
                      const float* __restrict__ bias,
                      float*       __restrict__ out)
{
    // vals[c*R + r] = f16 value of column c, block batch-row r.
    __shared__ __align__(16) __half vals[LDS_COLS * R];   // 65536 B

    const int tid  = threadIdx.x;
    const int row0 = blockIdx.x * R;

    // ---- Stage x rows into LDS as f16 (each thread owns one column) ----
    {
        const int c = tid;                     // NT == N_IN == 512
        float v[R];
        #pragma unroll
        for (int r = 0; r < R; ++r)
            v[r] = x[(row0 + r) * N_IN + c];   // coalesced per r
        __half2 p[R / 2];
        #pragma unroll
        for (int r = 0; r < R / 2; ++r)
            p[r] = __floats2half2_rn(v[2 * r], v[2 * r + 1]);
        *(uint4*)&vals[c * R] = *(const uint4*)p;   // one ds_write_b128
    }

    // ---- Preload layer-0 params while LDS staging drains (before barrier) ----
    int   idxA[K]; float wA[K]; float bA;
    {
        const int base = tid * K;              // l=0, h=tid
        #pragma unroll
        for (int q = 0; q < 4; ++q) {
            *(int4*)  &idxA[4 * q] = ((const int4*)  (link_idx + base))[q];
            *(float4*)&wA  [4 * q] = ((const float4*)(weights  + base))[q];
        }
        #pragma unroll
        for (int k = 0; k < K; ++k) idxA[k] <<= 4;   // byte offsets, once per layer
        bA = bias[tid];
    }

    __syncthreads();

    // ---- Layers (each thread owns one h; 8 batch rows in registers) ----
    #pragma unroll
    for (int l = 0; l < LAYERS; ++l) {
        // Prefetch next layer's params under this layer's gather/FMA work.
        int idxB[K]; float wB[K]; float bB = 0.0f;
        if (l < LAYERS - 1) {
            const int nb = ((l + 1) * H + tid) * K;
            #pragma unroll
            for (int q = 0; q < 4; ++q) {
                *(int4*)  &idxB[4 * q] = ((const int4*)  (link_idx + nb))[q];
                *(float4*)&wB  [4 * q] = ((const float4*)(weights  + nb))[q];
            }
            #pragma unroll
            for (int k = 0; k < K; ++k) idxB[k] <<= 4;
            bB = bias[(l + 1) * H + tid];
        }

        float acc[R];
        #pragma unroll
        for (int r = 0; r < R; ++r) acc[r] = bA;

        // ---- Gather in two pinned bursts of 8 ds_read_b128.
        // sched_barrier(0) stops the scheduler from sinking reads toward their
        // uses (R8 lesson): all 8 issue back-to-back -> 8 outstanding per wave,
        // x16 waves/CU keeps the LDS pipe fed. g[] statically indexed (full
        // unroll) so it stays in registers.
        uint4 g[8];
        #pragma unroll
        for (int half = 0; half < 2; ++half) {
            const int k0 = half * 8;
            #pragma unroll
            for (int j = 0; j < 8; ++j)
                g[j] = *(const uint4*)((const char*)vals + idxA[k0 + j]);
            __builtin_amdgcn_sched_barrier(0);   // pin: issue all 8 before any consume
            #pragma unroll
            for (int j = 0; j < 8; ++j) {
                const __half2* hp = (const __half2*)&g[j];
                const float wk = wA[k0 + j];
                #pragma unroll
                for (int r = 0; r < R / 2; ++r) {
                    const float2 f = __half22float2(hp[r]);   // folds into v_fma_mix_f32
                    acc[2 * r]     = fmaf(f.x, wk, acc[2 * r]);
                    acc[2 * r + 1] = fmaf(f.y, wk, acc[2 * r + 1]);
                }
            }
        }

        // sigmoid via v_rcp_f32 (~1 ulp) instead of the ~10-instr exact divide
        #pragma unroll
        for (int r = 0; r < R; ++r)
            acc[r] = __builtin_amdgcn_rcpf(1.0f + __expf(-acc[r]));

        if (l < LAYERS - 1) {
            __half2 p[R / 2];
            #pragma unroll
            for (int r = 0; r < R / 2; ++r)
                p[r] = __floats2half2_rn(acc[2 * r], acc[2 * r + 1]);
            *(uint4*)&vals[(N_IN + l * H + tid) * R] = *(const uint4*)p;
            __syncthreads();
            // rotate prefetched params in (full unroll -> register renaming, no moves)
            #pragma unroll
            for (int k = 0; k < K; ++k) { idxA[k] = idxB[k]; wA[k] = wB[k]; }
            bA = bB;
        } else {
            // final layer: coalesced fp32 stores (lanes -> consecutive h)
            #pragma unroll
            for (int r = 0; r < R; ++r)
                out[(row0 + r) * H + tid] = acc[r];
        }
    }
}

extern "C" void kernel_launch(void* const* d_in, const int* in_sizes, int n_in,
                              void* d_out, int out_size, void* d_ws, size_t ws_size,
                              hipStream_t stream) {
    const float* x        = (const float*)d_in[0];
    const int*   link_idx = (const int*)  d_in[1];
    const float* weights  = (const float*)d_in[2];
    const float* bias     = (const float*)d_in[3];
    float*       out      = (float*)d_out;

    ffn_fused_kernel<<<dim3(BATCH / R), dim3(NT), 0, stream>>>(x, link_idx, weights, bias, out);
}

// Round 7
// 118.897 us; speedup vs baseline: 1.0585x; 1.0585x over previous
//
#include <hip/hip_runtime.h>
#include <hip/hip_fp16.h>

// L=8 layers, H=512, K=16 links, N_IN=512, B=8192; out = last 512 cols (fp32).
#define LAYERS 8
#define H      512
#define K      16
#define N_IN   512
#define BATCH  8192
#define R      8      // batch rows per block; 8 x f16 = 16 B -> one ds_read_b128 per gather
#define NT     512    // 8 waves/block; 64 KB LDS -> 2 blocks/CU -> 16 waves/CU
// Layer l gathers from cols [0, 512+512*l); max l=7 -> cols < 4096. Layer 7's
// output is never gathered -> straight to global. LDS = 4096*16 B = 64 KB.
#define LDS_COLS 4096

// History:
//  R3/R4: NT=1024 spills regardless of __launch_bounds__. Stay at NT=512.
//  R5/R7: bank-group sort+stagger prep: conflicts only -12% (static lane perms
//    can't debias the 64-lane multinomial); prep dispatch cost ~10us e2e.
//  R8: g[2][4] rolling buffer, (NT,4): VGPR capped at 60, compiler collapsed
//    the queue. Dispatches 55-61us.
//  R9: burst-8 + sched_barrier(0), (NT,4): VGPR pinned to 64 -> SPILLED
//    (WRITE_SIZE 16->59MB, FETCH 10->26MB, dispatch 67us). Evidence: 2nd
//    launch_bounds arg acts like min-BLOCKS/CU here: (NT,4)=32 waves/CU=64
//    VGPR cap. (NT,2)=2 blocks/CU=128 cap -- what the burst needs (~104 live).
//  R10: R9 with __launch_bounds__(NT,2). Infra died twice ("container failed
//    twice") before any dispatch -- same flake as R1/R2 (R3 proved d_ws was
//    never the culprit: its workspace path ran fine). R11: resubmit unchanged.
//    Tripwire: if WRITE_SIZE >> 16.4MB, it still spilled -> revert.

__global__ __launch_bounds__(NT, 2)
void ffn_fused_kernel(const float* __restrict__ x,
                      const int*   __restrict__ link_idx,
                      const float* __restrict__ weights,
                      const float* __restrict__ bias,
                      float*       __restrict__ out)
{
    // vals[c*R + r] = f16 value of column c, block batch-row r.
    __shared__ __align__(16) __half vals[LDS_COLS * R];   // 65536 B

    const int tid  = threadIdx.x;
    const int row0 = blockIdx.x * R;

    // ---- Stage x rows into LDS as f16 (each thread owns one column) ----
    {
        const int c = tid;                     // NT == N_IN == 512
        float v[R];
        #pragma unroll
        for (int r = 0; r < R; ++r)
            v[r] = x[(row0 + r) * N_IN + c];   // coalesced per r
        __half2 p[R / 2];
        #pragma unroll
        for (int r = 0; r < R / 2; ++r)
            p[r] = __floats2half2_rn(v[2 * r], v[2 * r + 1]);
        *(uint4*)&vals[c * R] = *(const uint4*)p;   // one ds_write_b128
    }

    // ---- Preload layer-0 params while LDS staging drains (before barrier) ----
    int   idxA[K]; float wA[K]; float bA;
    {
        const int base = tid * K;              // l=0, h=tid
        #pragma unroll
        for (int q = 0; q < 4; ++q) {
            *(int4*)  &idxA[4 * q] = ((const int4*)  (link_idx + base))[q];
            *(float4*)&wA  [4 * q] = ((const float4*)(weights  + base))[q];
        }
        #pragma unroll
        for (int k = 0; k < K; ++k) idxA[k] <<= 4;   // byte offsets, once per layer
        bA = bias[tid];
    }

    __syncthreads();

    // ---- Layers (each thread owns one h; 8 batch rows in registers) ----
    #pragma unroll
    for (int l = 0; l < LAYERS; ++l) {
        // Prefetch next layer's params under this layer's gather/FMA work.
        int idxB[K]; float wB[K]; float bB = 0.0f;
        if (l < LAYERS - 1) {
            const int nb = ((l + 1) * H + tid) * K;
            #pragma unroll
            for (int q = 0; q < 4; ++q) {
                *(int4*)  &idxB[4 * q] = ((const int4*)  (link_idx + nb))[q];
                *(float4*)&wB  [4 * q] = ((const float4*)(weights  + nb))[q];
            }
            #pragma unroll
            for (int k = 0; k < K; ++k) idxB[k] <<= 4;
            bB = bias[(l + 1) * H + tid];
        }

        float acc[R];
        #pragma unroll
        for (int r = 0; r < R; ++r) acc[r] = bA;

        // ---- Gather in two pinned bursts of 8 ds_read_b128.
        // sched_barrier(0) stops the scheduler from sinking reads toward their
        // uses (R8 lesson): all 8 issue back-to-back -> 8 outstanding per wave,
        // x16 waves/CU keeps the LDS pipe fed. g[] statically indexed (full
        // unroll) so it stays in registers. Needs ~104 VGPR -> (NT,2) cap 128.
        uint4 g[8];
        #pragma unroll
        for (int half = 0; half < 2; ++half) {
            const int k0 = half * 8;
            #pragma unroll
            for (int j = 0; j < 8; ++j)
                g[j] = *(const uint4*)((const char*)vals + idxA[k0 + j]);
            __builtin_amdgcn_sched_barrier(0);   // pin: issue all 8 before any consume
            #pragma unroll
            for (int j = 0; j < 8; ++j) {
                const __half2* hp = (const __half2*)&g[j];
                const float wk = wA[k0 + j];
                #pragma unroll
                for (int r = 0; r < R / 2; ++r) {
                    const float2 f = __half22float2(hp[r]);   // folds into v_fma_mix_f32
                    acc[2 * r]     = fmaf(f.x, wk, acc[2 * r]);
                    acc[2 * r + 1] = fmaf(f.y, wk, acc[2 * r + 1]);
                }
            }
        }

        // sigmoid via v_rcp_f32 (~1 ulp) instead of the ~10-instr exact divide
        #pragma unroll
        for (int r = 0; r < R; ++r)
            acc[r] = __builtin_amdgcn_rcpf(1.0f + __expf(-acc[r]));

        if (l < LAYERS - 1) {
            __half2 p[R / 2];
            #pragma unroll
            for (int r = 0; r < R / 2; ++r)
                p[r] = __floats2half2_rn(acc[2 * r], acc[2 * r + 1]);
            *(uint4*)&vals[(N_IN + l * H + tid) * R] = *(const uint4*)p;
            __syncthreads();
            // rotate prefetched params in (full unroll -> register renaming, no moves)
            #pragma unroll
            for (int k = 0; k < K; ++k) { idxA[k] = idxB[k]; wA[k] = wB[k]; }
            bA = bB;
        } else {
            // final layer: coalesced fp32 stores (lanes -> consecutive h)
            #pragma unroll
            for (int r = 0; r < R; ++r)
                out[(row0 + r) * H + tid] = acc[r];
        }
    }
}

extern "C" void kernel_launch(void* const* d_in, const int* in_sizes, int n_in,
                              void* d_out, int out_size, void* d_ws, size_t ws_size,
                              hipStream_t stream) {
    const float* x        = (const float*)d_in[0];
    const int*   link_idx = (const int*)  d_in[1];
    const float* weights  = (const float*)d_in[2];
    const float* bias     = (const float*)d_in[3];
    float*       out      = (float*)d_out;

    ffn_fused_kernel<<<dim3(BATCH / R), dim3(NT), 0, stream>>>(x, link_idx, weights, bias, out);
}